// Round 6
// baseline (118.191 us; speedup 1.0000x reference)
//
#include <hip/hip_runtime.h>
#include <hip/hip_bf16.h>
#include <math.h>

// Problem constants
#define N_   64
#define T_   1000
#define E_   512
#define A_   256
#define O_   80
#define S_   64
#define H_   1024
#define G4_  4096
#define KC_  31   // conv kernel size, K//2 = 15

__device__ __forceinline__ float sigmoidf_(float x) { return 1.f / (1.f + __expf(-x)); }
__device__ __forceinline__ float softsignf_(float x) { return x / (1.f + fabsf(x)); }

// ---------------------------------------------------------------------------
// K1: fused attention (logits + softmax + context) + prenet + x assembly.
// grid 64 blocks (one per n) x 1024 threads (16 waves).
// Wave w = (aq = w>>2, kw = w&3): lane = local a (64), k-chunk = kw*128.
// enc rows t=0..9 staged once in LDS; context reuses them (no global re-read).
// plds (40 KB) holds logits partials, then is reused for pre1/pre2 scratch.
// ---------------------------------------------------------------------------
__global__ __launch_bounds__(1024) void att_prenet_kernel(
    const float* __restrict__ enc,
    const float* __restrict__ dec_in,
    const float* __restrict__ spkr,
    const int*   __restrict__ lengths,
    const float* __restrict__ w_enc,
    const float* __restrict__ b_enc,
    const float* __restrict__ w_spkr,
    const float* __restrict__ conv_w,
    const float* __restrict__ w_proj,
    const float* __restrict__ w_p1,
    const float* __restrict__ b_p1,
    const float* __restrict__ w_p2,
    const float* __restrict__ b_p2,
    float* __restrict__ xbuf) {
  int n    = blockIdx.x;
  int tid  = threadIdx.x;
  int lane = tid & 63;
  int w    = tid >> 6;        // 0..15
  int aq   = w >> 2;          // 0..3
  int kw   = w & 3;           // 0..3
  int a    = aq * 64 + lane;

  __shared__ float er[5120];      // enc rows t=0..9           (20 KB)
  __shared__ float plds[10240];   // partials -> pre1/pp2      (40 KB)
  __shared__ float sp[S_];
  __shared__ float bsl[A_];
  __shared__ float att[10];
  __shared__ float incat[144];
  __shared__ float lgred[10][4];

  if (tid < S_) sp[tid] = spkr[n * S_ + tid];
  if (tid < O_) incat[tid] = dec_in[n * O_ + tid];
  else if (tid < 144) incat[tid] = spkr[n * S_ + tid - O_];
  {
    const float4* src = (const float4*)(enc + (size_t)n * T_ * E_);
    float4* dst = (float4*)er;
    for (int i = tid; i < 1280; i += 1024) dst[i] = src[i];
  }
  __syncthreads();

  // bias_spkr (per a)
  if (tid < A_) {
    float b = 0.f;
    #pragma unroll 8
    for (int s = 0; s < S_; ++s) b = fmaf(sp[s], w_spkr[s * A_ + tid], b);
    bsl[tid] = softsignf_(b);
  }

  // logits main loop: this wave's 128-k chunk, 10 t's per w_enc load
  float acc[10];
  #pragma unroll
  for (int t = 0; t < 10; ++t) acc[t] = 0.f;
  const int kbase = kw * 128;
  const float* wcol = w_enc + a;
  #pragma unroll 8
  for (int k = 0; k < 128; ++k) {
    float we = wcol[(size_t)(kbase + k) * A_];
    #pragma unroll
    for (int t = 0; t < 10; ++t)
      acc[t] = fmaf(er[t * E_ + kbase + k], we, acc[t]);
  }
  #pragma unroll
  for (int t = 0; t < 10; ++t) plds[w * 640 + t * 64 + lane] = acc[t];
  __syncthreads();

  // logit reduce: 2560 (t,a) pairs; each wave covers one (t,aq) per pass
  #pragma unroll
  for (int it = 0; it < 3; ++it) {
    int idx = tid + it * 1024;
    if (idx < 2560) {
      int t   = idx >> 8;
      int aa  = idx & 255;
      int aaq = aa >> 6;
      int al  = aa & 63;
      float p = plds[(aaq * 4 + 0) * 640 + t * 64 + al]
              + plds[(aaq * 4 + 1) * 640 + t * 64 + al]
              + plds[(aaq * 4 + 2) * 640 + t * 64 + al]
              + plds[(aaq * 4 + 3) * 640 + t * 64 + al];
      float e = softsignf_(p + b_enc[aa]) + bsl[aa] + conv_w[aa * KC_ + (15 - t)];
      float l = tanhf(e) * w_proj[aa];
      #pragma unroll
      for (int off = 32; off > 0; off >>= 1) l += __shfl_down(l, off);
      if (al == 0) lgred[t][aaq] = l;
    }
  }
  __syncthreads();

  if (tid == 0) {
    int lim = lengths[n] - 1; if (lim < 0) lim = 0;
    int tmax = lim < 9 ? lim : 9;
    float lg[10];
    float m = -1e30f;
    for (int t = 0; t <= tmax; ++t) {
      lg[t] = lgred[t][0] + lgred[t][1] + lgred[t][2] + lgred[t][3];
      m = fmaxf(m, lg[t]);
    }
    float ssum = 0.f;
    for (int t = 0; t <= tmax; ++t) { float x = __expf(lg[t] - m); att[t] = x; ssum += x; }
    float inv = 1.f / fmaxf(ssum, 1e-12f);
    for (int t = 0; t <= tmax; ++t) att[t] *= inv;
    for (int t = tmax + 1; t < 10; ++t) att[t] = 0.f;
  }
  __syncthreads();

  // context (from LDS er) by tid<512; pre1 by tid>=512 (plds now free)
  if (tid < 512) {
    float c = 0.f;
    #pragma unroll
    for (int t = 0; t < 10; ++t) c = fmaf(att[t], er[t * E_ + tid], c);
    xbuf[n * 832 + 256 + tid] = c;
    if (tid < S_) xbuf[n * 832 + 768 + tid] = sp[tid];
  } else {
    int c = tid - 512;
    float v = b_p1[c];
    #pragma unroll 8
    for (int k = 0; k < 144; ++k) v = fmaf(incat[k], w_p1[k * 512 + c], v);
    plds[c] = fmaxf(v, 0.f);     // pre1
  }
  __syncthreads();

  // pre2 = relu(pre1 @ w_p2 + b_p2): 4-way K split (128 each)
  {
    int c  = tid & 255;
    int kq = tid >> 8;
    float v = 0.f;
    #pragma unroll 8
    for (int k = kq * 128; k < kq * 128 + 128; ++k)
      v = fmaf(plds[k], w_p2[k * A_ + c], v);
    plds[1024 + kq * 256 + c] = v;
  }
  __syncthreads();
  if (tid < A_) {
    float v = b_p2[tid] + plds[1024 + tid] + plds[1280 + tid]
            + plds[1536 + tid] + plds[1792 + tid];
    xbuf[n * 832 + tid] = fmaxf(v, 0.f);
  }
}

// ---------------------------------------------------------------------------
// GEMM (R3-proven): G[64 x 4096] = X[64 x K] @ W[K x 4096] + b1 + b2,
// i/g/o cols only. grid 192 blocks (16-col tiles) x 512 threads.
// kh = tid>>8 owns half of K (LDS-reduced). W -> registers wreg[32]
// (no spill at 512 thr; 768-thr variant spilled — R4). X staged in LDS,
// double-buffered, software-pipelined.
// ---------------------------------------------------------------------------
__global__ __launch_bounds__(512) void gemm_gates_kernel(
    const float* __restrict__ X, int ldx, int K,
    const float* __restrict__ W,
    const float* __restrict__ b1,
    const float* __restrict__ b2,
    float* __restrict__ G) {
  int bt = blockIdx.x;
  int c0 = bt * 16; if (c0 >= 1024) c0 += 1024;   // skip dead f-gate columns
  int tid = threadIdx.x;
  int kh  = tid >> 8;        // K half
  int lt  = tid & 255;
  int tr  = lt >> 4;         // 0..15 row group
  int tc  = lt & 15;         // 0..15 col
  int c   = c0 + tc;
  int Kh  = K >> 1;          // 416 / 512
  int kbeg = kh * Kh;
  int NC  = Kh >> 5;

  int rr  = lt & 63;
  int kb8 = (lt >> 6) << 3;

  __shared__ float xs[2][2][32][64];   // [kh][buf][kk][r], 32 KB
  __shared__ float red[16][16][4];     // 4 KB

  const float* xsrc = X + (size_t)rr * ldx + kbeg + kb8;

  float4 xv0 = ((const float4*)xsrc)[0];
  float4 xv1 = ((const float4*)(xsrc + 4))[0];
  {
    float* d = &xs[kh][0][kb8][rr];
    d[0]   = xv0.x; d[64]  = xv0.y; d[128] = xv0.z; d[192] = xv0.w;
    d[256] = xv1.x; d[320] = xv1.y; d[384] = xv1.z; d[448] = xv1.w;
  }
  __syncthreads();

  float acc0 = 0.f, acc1 = 0.f, acc2 = 0.f, acc3 = 0.f;
  for (int ch = 0; ch < NC; ++ch) {
    int buf = ch & 1;
    float wreg[32];
    const float* wp = W + (size_t)(kbeg + ch * 32) * G4_ + c;
    #pragma unroll
    for (int kk = 0; kk < 32; ++kk) wreg[kk] = wp[(size_t)kk * G4_];
    bool more = (ch + 1 < NC);
    if (more) {
      const float* s = xsrc + (ch + 1) * 32;
      xv0 = ((const float4*)s)[0];
      xv1 = ((const float4*)(s + 4))[0];
    }
    const float* xb = &xs[kh][buf][0][tr * 4];
    #pragma unroll
    for (int kk = 0; kk < 32; ++kk) {
      float4 xv = *(const float4*)(xb + kk * 64);
      acc0 = fmaf(xv.x, wreg[kk], acc0);
      acc1 = fmaf(xv.y, wreg[kk], acc1);
      acc2 = fmaf(xv.z, wreg[kk], acc2);
      acc3 = fmaf(xv.w, wreg[kk], acc3);
    }
    if (more) {
      float* d = &xs[kh][buf ^ 1][kb8][rr];
      d[0]   = xv0.x; d[64]  = xv0.y; d[128] = xv0.z; d[192] = xv0.w;
      d[256] = xv1.x; d[320] = xv1.y; d[384] = xv1.z; d[448] = xv1.w;
    }
    __syncthreads();
  }

  if (kh == 1) {
    red[tr][tc][0] = acc0; red[tr][tc][1] = acc1;
    red[tr][tc][2] = acc2; red[tr][tc][3] = acc3;
  }
  __syncthreads();
  if (kh == 0) {
    float bb = b1[c] + b2[c];
    int r = tr * 4;
    G[(size_t)(r + 0) * G4_ + c] = acc0 + red[tr][tc][0] + bb;
    G[(size_t)(r + 1) * G4_ + c] = acc1 + red[tr][tc][1] + bb;
    G[(size_t)(r + 2) * G4_ + c] = acc2 + red[tr][tc][2] + bb;
    G[(size_t)(r + 3) * G4_ + c] = acc3 + red[tr][tc][3] + bb;
  }
}

// ---------------------------------------------------------------------------
// LSTM activation (zero initial state, f-gate dead):
// h = sigmoid(o) * tanh( sigmoid(i) * tanh(g) ), grid 256 x 256.
// ---------------------------------------------------------------------------
__global__ void lstm_act_kernel(const float* __restrict__ G, float* __restrict__ H) {
  int idx = blockIdx.x * 256 + threadIdx.x;   // 65536 = 64 n x 1024 j
  int n = idx >> 10;
  int j = idx & 1023;
  float gi = G[(size_t)n * G4_ + j];
  float gg = G[(size_t)n * G4_ + 2048 + j];
  float go = G[(size_t)n * G4_ + 3072 + j];
  float cc = sigmoidf_(gi) * tanhf(gg);
  H[n * H_ + j] = sigmoidf_(go) * tanhf(cc);
}

// ---------------------------------------------------------------------------
// K5: fused h2-activation + output GEMM. out[n,c] = [h2|ctx] @ w_out + b_out.
// grid 64 blocks = (8 n-groups x 8 col-groups of 20) x 512 threads.
// Each block reads only its 20-col w_out slice (123 KB) -> 7.9 MB total.
// ---------------------------------------------------------------------------
#define DLP 1544   // 1536 + 8 pad
__global__ __launch_bounds__(512) void out_kernel(
    const float* __restrict__ gates,
    const float* __restrict__ xbuf,
    const float* __restrict__ w_out,
    const float* __restrict__ b_out,
    float* __restrict__ out) {
  int bn = blockIdx.x >> 3;          // n-group: rows bn*8 .. +8
  int c0 = (blockIdx.x & 7) * 20;    // col slice
  int tid = threadIdx.x;
  __shared__ float dl[8][DLP];
  __shared__ float pp[3][160];

  for (int idx = tid; idx < 8 * 1536; idx += 512) {
    int nl = idx / 1536;
    int k  = idx % 1536;
    int n  = bn * 8 + nl;
    if (k < 1024) {
      float gi = gates[(size_t)n * G4_ + k];
      float gg = gates[(size_t)n * G4_ + 2048 + k];
      float go = gates[(size_t)n * G4_ + 3072 + k];
      dl[nl][k] = sigmoidf_(go) * tanhf(sigmoidf_(gi) * tanhf(gg));
    } else {
      dl[nl][k] = xbuf[n * 832 + 256 + (k - 1024)];
    }
  }
  __syncthreads();

  if (tid < 480) {
    int kq = tid / 160;              // 0..2, k in [kq*512, kq*512+512)
    int o  = tid % 160;
    int nl = o / 20;
    int cl = o % 20;
    const float* wp = w_out + (size_t)(kq * 512) * 160 + c0 + cl;
    const float* dp = &dl[nl][kq * 512];
    float acc = 0.f;
    #pragma unroll 8
    for (int k = 0; k < 512; ++k) acc = fmaf(dp[k], wp[(size_t)k * 160], acc);
    pp[kq][o] = acc;
  }
  __syncthreads();
  if (tid < 160) {
    int nl = tid / 20;
    int cl = tid % 20;
    float v = b_out[c0 + cl] + pp[0][tid] + pp[1][tid] + pp[2][tid];
    out[(size_t)(bn * 8 + nl) * 160 + c0 + cl] = v;
  }
}

// ---------------------------------------------------------------------------
extern "C" void kernel_launch(void* const* d_in, const int* in_sizes, int n_in,
                              void* d_out, int out_size, void* d_ws, size_t ws_size,
                              hipStream_t stream) {
  const float* input_enc = (const float*)d_in[0];
  const float* input_dec = (const float*)d_in[1];
  const float* spkr_vec  = (const float*)d_in[2];
  const int*   lengths   = (const int*)  d_in[3];
  const float* w_enc     = (const float*)d_in[4];
  const float* b_enc     = (const float*)d_in[5];
  const float* w_spkr    = (const float*)d_in[6];
  const float* conv_w    = (const float*)d_in[7];
  const float* w_proj    = (const float*)d_in[8];
  // d_in[9]  b_proj: constant across t -> cancels in softmax
  const float* w_p1      = (const float*)d_in[10];
  const float* b_p1      = (const float*)d_in[11];
  const float* w_p2      = (const float*)d_in[12];
  const float* b_p2      = (const float*)d_in[13];
  const float* w_ih0     = (const float*)d_in[14];
  // d_in[15] w_hh0: dead
  const float* b_ih0     = (const float*)d_in[16];
  const float* b_hh0     = (const float*)d_in[17];
  const float* w_ih1     = (const float*)d_in[18];
  // d_in[19] w_hh1: dead
  const float* b_ih1     = (const float*)d_in[20];
  const float* b_hh1     = (const float*)d_in[21];
  const float* w_out     = (const float*)d_in[22];
  const float* b_out     = (const float*)d_in[23];

  float* ws    = (float*)d_ws;
  float* xbuf  = ws + 4096;     // 64*832
  float* gates = ws + 65536;    // 64*4096
  float* h1    = ws + 327680;   // 64*1024
  float* out   = (float*)d_out; // 64*2*80

  hipLaunchKernelGGL(att_prenet_kernel, dim3(64), dim3(1024), 0, stream,
                     input_enc, input_dec, spkr_vec, lengths,
                     w_enc, b_enc, w_spkr, conv_w, w_proj,
                     w_p1, b_p1, w_p2, b_p2, xbuf);
  hipLaunchKernelGGL(gemm_gates_kernel, dim3(192), dim3(512), 0, stream,
                     xbuf, 832, 832, w_ih0, b_ih0, b_hh0, gates);
  hipLaunchKernelGGL(lstm_act_kernel, dim3(256), dim3(256), 0, stream, gates, h1);
  hipLaunchKernelGGL(gemm_gates_kernel, dim3(192), dim3(512), 0, stream,
                     h1, 1024, 1024, w_ih1, b_ih1, b_hh1, gates);
  hipLaunchKernelGGL(out_kernel, dim3(64), dim3(512), 0, stream,
                     gates, xbuf, w_out, b_out, out);
}

// Round 7
// 98.596 us; speedup vs baseline: 1.1987x; 1.1987x over previous
//
#include <hip/hip_runtime.h>
#include <hip/hip_bf16.h>
#include <math.h>

// Problem constants
#define N_   64
#define T_   1000
#define E_   512
#define A_   256
#define O_   80
#define S_   64
#define H_   1024
#define G4_  4096
#define KC_  31   // conv kernel size, K//2 = 15

__device__ __forceinline__ float sigmoidf_(float x) { return 1.f / (1.f + __expf(-x)); }
__device__ __forceinline__ float softsignf_(float x) { return x / (1.f + fabsf(x)); }

// ---------------------------------------------------------------------------
// K1a: attention logits. grid (64 n, 4 aq) x 512 threads (8 waves).
// Lane al = local a (64 per block); wave kw owns k-chunk [kw*64, kw*64+64).
// Each w_enc load feeds 10 FMAs (one per timestep) -> high ILP; 256 blocks
// x 8 waves keeps the whole GPU latency-hiding (fusion to 64 blocks was a
// measured -19 us regression in R6).
// ---------------------------------------------------------------------------
__global__ __launch_bounds__(512) void logits_kernel(
    const float* __restrict__ enc,
    const float* __restrict__ spkr,
    const float* __restrict__ w_enc,
    const float* __restrict__ b_enc,
    const float* __restrict__ w_spkr,
    const float* __restrict__ conv_w,
    const float* __restrict__ w_proj,
    float* __restrict__ part) {
  int n  = blockIdx.x;
  int aq = blockIdx.y;
  int tid = threadIdx.x;
  int al = tid & 63;
  int kw = tid >> 6;        // 0..7
  int a  = aq * 64 + al;

  __shared__ float smem[5120];   // er[10][512], later reused as part_l[8][10][64]
  __shared__ float sp[S_];
  __shared__ float bsl[S_];

  if (tid < S_) sp[tid] = spkr[n * S_ + tid];
  // stage enc rows t=0..9 as float4 (1280 float4s / 512 threads)
  {
    const float4* src = (const float4*)(enc + (size_t)n * T_ * E_);
    float4* dst = (float4*)smem;
    for (int i = tid; i < 1280; i += 512) dst[i] = src[i];
  }
  __syncthreads();

  // bias_spkr for this a, by first 64 threads
  if (tid < S_) {
    float b = 0.f;
    #pragma unroll 8
    for (int s = 0; s < S_; ++s) b += sp[s] * w_spkr[s * A_ + aq * 64 + tid];
    bsl[tid] = softsignf_(b);
  }

  // main loop: this wave's 64-k chunk, 10 t's per load
  float acc[10];
  #pragma unroll
  for (int t = 0; t < 10; ++t) acc[t] = 0.f;
  const int kbase = kw * 64;
  const float* wcol = w_enc + a;
  #pragma unroll 8
  for (int k = 0; k < 64; ++k) {
    float we = wcol[(size_t)(kbase + k) * A_];
    #pragma unroll
    for (int t = 0; t < 10; ++t)
      acc[t] = fmaf(smem[t * E_ + kbase + k], we, acc[t]);
  }

  __syncthreads();   // done reading er; reuse smem for partials
  #pragma unroll
  for (int t = 0; t < 10; ++t) smem[(kw * 10 + t) * 64 + al] = acc[t];
  __syncthreads();

  // epilogue: (t, al) pairs; 512 threads cover t=0..7 then t=8..9
  #pragma unroll
  for (int tb = 0; tb < 10; tb += 8) {
    int t = tb + kw;
    if (t < 10 && (tb == 0 || kw < 2)) {
      float p = b_enc[a];
      #pragma unroll
      for (int w = 0; w < 8; ++w) p += smem[(w * 10 + t) * 64 + al];
      float e = softsignf_(p) + bsl[al] + conv_w[a * KC_ + (15 - t)];
      float l = tanhf(e) * w_proj[a];
      #pragma unroll
      for (int off = 32; off > 0; off >>= 1) l += __shfl_down(l, off);
      if (al == 0) part[(n * 10 + t) * 4 + aq] = l;
    }
  }
}

// ---------------------------------------------------------------------------
// K1b: softmax (10 wide) + context + prenet + assemble x = [pre2|ctx|spkr].
// grid 64 blocks x 512 threads.
// ---------------------------------------------------------------------------
__global__ __launch_bounds__(512) void ctx_prenet_kernel(
    const float* __restrict__ enc,
    const float* __restrict__ dec_in,
    const float* __restrict__ spkr,
    const int*   __restrict__ lengths,
    const float* __restrict__ part,
    const float* __restrict__ w_p1,
    const float* __restrict__ b_p1,
    const float* __restrict__ w_p2,
    const float* __restrict__ b_p2,
    float* __restrict__ xbuf) {
  int n = blockIdx.x;
  int tid = threadIdx.x;
  __shared__ float att[10];
  __shared__ float incat[O_ + S_];   // 144
  __shared__ float pre1[512];
  __shared__ float pp2[2][A_];

  if (tid < S_) {
    float s = spkr[n * S_ + tid];
    incat[O_ + tid] = s;
    xbuf[n * 832 + 768 + tid] = s;
  }
  if (tid < O_) incat[tid] = dec_in[n * O_ + tid];
  if (tid == 0) {
    int lim = lengths[n] - 1; if (lim < 0) lim = 0;
    int tmax = lim < 9 ? lim : 9;
    float lg[10];
    float m = -1e30f;
    for (int t = 0; t <= tmax; ++t) {
      const float* p = &part[(n * 10 + t) * 4];
      lg[t] = p[0] + p[1] + p[2] + p[3];
      m = fmaxf(m, lg[t]);
    }
    float ssum = 0.f;
    for (int t = 0; t <= tmax; ++t) { float w = __expf(lg[t] - m); att[t] = w; ssum += w; }
    float inv = 1.f / fmaxf(ssum, 1e-12f);
    for (int t = 0; t <= tmax; ++t) att[t] *= inv;
    for (int t = tmax + 1; t < 10; ++t) att[t] = 0.f;
  }
  __syncthreads();

  // context -> xbuf[n][256 + e]   (512 threads, 1 element each)
  {
    float c = 0.f;
    #pragma unroll
    for (int t = 0; t < 10; ++t)
      c = fmaf(att[t], enc[(size_t)n * T_ * E_ + t * E_ + tid], c);
    xbuf[n * 832 + 256 + tid] = c;
  }

  // pre1 = relu(incat @ w_p1 + b_p1)   (144 x 512), 1 col/thread
  {
    float v = b_p1[tid];
    #pragma unroll 8
    for (int k = 0; k < O_ + S_; ++k) v = fmaf(incat[k], w_p1[k * 512 + tid], v);
    pre1[tid] = fmaxf(v, 0.f);
  }
  __syncthreads();

  // pre2 = relu(pre1 @ w_p2 + b_p2)    (512 x 256), 2-way K split
  {
    int c  = tid & 255;
    int kh = tid >> 8;
    float v = 0.f;
    #pragma unroll 8
    for (int k = kh * 256; k < kh * 256 + 256; ++k)
      v = fmaf(pre1[k], w_p2[k * A_ + c], v);
    pp2[kh][c] = v;
  }
  __syncthreads();
  if (tid < A_) {
    float v = b_p2[tid] + pp2[0][tid] + pp2[1][tid];
    xbuf[n * 832 + tid] = fmaxf(v, 0.f);
  }
}

// ---------------------------------------------------------------------------
// GEMM: G[64 x 4096] = X[64 x K] @ W[K x 4096] + b1 + b2, only i/g/o columns.
// grid 192 blocks (16-col tiles over the 3072 live cols) x 512 threads.
// In-block K-split (kh = tid>>8 owns half of K), LDS reduce at the end.
// W loaded straight to registers wreg[32] (wave-coalesced, L1-deduped; no
// spill at 512 threads — the 768-thread variant spilled, R4). X chunk staged
// to LDS, software-pipelined: next chunk global->reg before compute,
// ds_write after, one barrier per chunk.
// ---------------------------------------------------------------------------
__global__ __launch_bounds__(512) void gemm_gates_kernel(
    const float* __restrict__ X, int ldx, int K,
    const float* __restrict__ W,
    const float* __restrict__ b1,
    const float* __restrict__ b2,
    float* __restrict__ G) {
  int bt = blockIdx.x;
  int c0 = bt * 16; if (c0 >= 1024) c0 += 1024;   // skip dead f-gate columns
  int tid = threadIdx.x;
  int kh  = tid >> 8;        // K half
  int lt  = tid & 255;
  int tr  = lt >> 4;         // 0..15 row group
  int tc  = lt & 15;         // 0..15 col
  int c   = c0 + tc;
  int Kh  = K >> 1;          // 416 / 512 (both multiples of 32)
  int kbeg = kh * Kh;
  int NC  = Kh >> 5;

  // staging mapping: lane -> row, quarter -> k-octet (writes 2-way-alias free)
  int rr  = lt & 63;
  int kb8 = (lt >> 6) << 3;

  __shared__ float xs[2][2][32][64];   // [kh][buf][kk][r], 32 KB
  __shared__ float red[16][16][4];     // 4 KB

  const float* xsrc = X + (size_t)rr * ldx + kbeg + kb8;

  float4 xv0 = ((const float4*)xsrc)[0];
  float4 xv1 = ((const float4*)(xsrc + 4))[0];
  {
    float* d = &xs[kh][0][kb8][rr];
    d[0]   = xv0.x; d[64]  = xv0.y; d[128] = xv0.z; d[192] = xv0.w;
    d[256] = xv1.x; d[320] = xv1.y; d[384] = xv1.z; d[448] = xv1.w;
  }
  __syncthreads();

  float acc0 = 0.f, acc1 = 0.f, acc2 = 0.f, acc3 = 0.f;
  for (int ch = 0; ch < NC; ++ch) {
    int buf = ch & 1;
    // W for current chunk -> registers (16 consecutive floats per wave-row,
    // 4 tr-groups read identical addresses -> coalesced + L1)
    float wreg[32];
    const float* wp = W + (size_t)(kbeg + ch * 32) * G4_ + c;
    #pragma unroll
    for (int kk = 0; kk < 32; ++kk) wreg[kk] = wp[(size_t)kk * G4_];
    // issue next chunk's X loads early (latency hides under compute)
    bool more = (ch + 1 < NC);
    if (more) {
      const float* s = xsrc + (ch + 1) * 32;
      xv0 = ((const float4*)s)[0];
      xv1 = ((const float4*)(s + 4))[0];
    }
    // compute: 32 x (16-way-broadcast b128 + 4 FMA)
    const float* xb = &xs[kh][buf][0][tr * 4];
    #pragma unroll
    for (int kk = 0; kk < 32; ++kk) {
      float4 xv = *(const float4*)(xb + kk * 64);
      acc0 = fmaf(xv.x, wreg[kk], acc0);
      acc1 = fmaf(xv.y, wreg[kk], acc1);
      acc2 = fmaf(xv.z, wreg[kk], acc2);
      acc3 = fmaf(xv.w, wreg[kk], acc3);
    }
    if (more) {
      float* d = &xs[kh][buf ^ 1][kb8][rr];
      d[0]   = xv0.x; d[64]  = xv0.y; d[128] = xv0.z; d[192] = xv0.w;
      d[256] = xv1.x; d[320] = xv1.y; d[384] = xv1.z; d[448] = xv1.w;
    }
    __syncthreads();
  }

  if (kh == 1) {
    red[tr][tc][0] = acc0; red[tr][tc][1] = acc1;
    red[tr][tc][2] = acc2; red[tr][tc][3] = acc3;
  }
  __syncthreads();
  if (kh == 0) {
    float bb = b1[c] + b2[c];
    int r = tr * 4;
    G[(size_t)(r + 0) * G4_ + c] = acc0 + red[tr][tc][0] + bb;
    G[(size_t)(r + 1) * G4_ + c] = acc1 + red[tr][tc][1] + bb;
    G[(size_t)(r + 2) * G4_ + c] = acc2 + red[tr][tc][2] + bb;
    G[(size_t)(r + 3) * G4_ + c] = acc3 + red[tr][tc][3] + bb;
  }
}

// ---------------------------------------------------------------------------
// LSTM activation (zero initial state, f-gate dead):
// h = sigmoid(o) * tanh( sigmoid(i) * tanh(g) ), grid 256 x 256.
// ---------------------------------------------------------------------------
__global__ void lstm_act_kernel(const float* __restrict__ G, float* __restrict__ H) {
  int idx = blockIdx.x * 256 + threadIdx.x;   // 65536 = 64 n x 1024 j
  int n = idx >> 10;
  int j = idx & 1023;
  float gi = G[(size_t)n * G4_ + j];
  float gg = G[(size_t)n * G4_ + 2048 + j];
  float go = G[(size_t)n * G4_ + 3072 + j];
  float cc = sigmoidf_(gi) * tanhf(gg);
  H[n * H_ + j] = sigmoidf_(go) * tanhf(cc);
}

// ---------------------------------------------------------------------------
// K6: fused h2 activation + output GEMM. grid 64 x 1024 threads.
// dec = [h2 (1024) | context (512)], out[n,c] = dec @ w_out + b_out.
// 6-way K split (256 k each) + LDS reduce. (R3-measured best; the 8x8
// split-grid variant was not faster.)
// ---------------------------------------------------------------------------
__global__ __launch_bounds__(1024) void out_kernel(
    const float* __restrict__ G1,
    const float* __restrict__ xbuf,
    const float* __restrict__ w_out,
    const float* __restrict__ b_out,
    float* __restrict__ out) {
  int n = blockIdx.x;
  int tid = threadIdx.x;
  __shared__ float dl[1536];
  __shared__ float pp[6][160];
  {   // h2 activation, 1 element/thread
    float gi = G1[(size_t)n * G4_ + tid];
    float gg = G1[(size_t)n * G4_ + 2048 + tid];
    float go = G1[(size_t)n * G4_ + 3072 + tid];
    dl[tid] = sigmoidf_(go) * tanhf(sigmoidf_(gi) * tanhf(gg));
  }
  if (tid < E_) dl[1024 + tid] = xbuf[n * 832 + 256 + tid];
  __syncthreads();
  if (tid < 960) {
    int c  = tid % 160;
    int kq = tid / 160;
    float acc = 0.f;
    const float* wp = w_out + (size_t)(kq * 256) * 160 + c;
    const float* dp = dl + kq * 256;
    #pragma unroll 8
    for (int k = 0; k < 256; ++k) acc = fmaf(dp[k], wp[(size_t)k * 160], acc);
    pp[kq][c] = acc;
  }
  __syncthreads();
  if (tid < 160) {
    float r = b_out[tid] + pp[0][tid] + pp[1][tid] + pp[2][tid]
            + pp[3][tid] + pp[4][tid] + pp[5][tid];
    out[n * 160 + tid] = r;
  }
}

// ---------------------------------------------------------------------------
extern "C" void kernel_launch(void* const* d_in, const int* in_sizes, int n_in,
                              void* d_out, int out_size, void* d_ws, size_t ws_size,
                              hipStream_t stream) {
  const float* input_enc = (const float*)d_in[0];
  const float* input_dec = (const float*)d_in[1];
  const float* spkr_vec  = (const float*)d_in[2];
  const int*   lengths   = (const int*)  d_in[3];
  const float* w_enc     = (const float*)d_in[4];
  const float* b_enc     = (const float*)d_in[5];
  const float* w_spkr    = (const float*)d_in[6];
  const float* conv_w    = (const float*)d_in[7];
  const float* w_proj    = (const float*)d_in[8];
  // d_in[9]  b_proj: constant across t -> cancels in softmax
  const float* w_p1      = (const float*)d_in[10];
  const float* b_p1      = (const float*)d_in[11];
  const float* w_p2      = (const float*)d_in[12];
  const float* b_p2      = (const float*)d_in[13];
  const float* w_ih0     = (const float*)d_in[14];
  // d_in[15] w_hh0: dead
  const float* b_ih0     = (const float*)d_in[16];
  const float* b_hh0     = (const float*)d_in[17];
  const float* w_ih1     = (const float*)d_in[18];
  // d_in[19] w_hh1: dead
  const float* b_ih1     = (const float*)d_in[20];
  const float* b_hh1     = (const float*)d_in[21];
  const float* w_out     = (const float*)d_in[22];
  const float* b_out     = (const float*)d_in[23];

  float* ws    = (float*)d_ws;
  float* part  = ws;            // 64*10*4   floats
  float* xbuf  = ws + 4096;     // 64*832
  float* gates = ws + 65536;    // 64*4096
  float* h1    = ws + 327680;   // 64*1024
  float* out   = (float*)d_out; // 64*2*80

  hipLaunchKernelGGL(logits_kernel, dim3(64, 4), dim3(512), 0, stream,
                     input_enc, spkr_vec, w_enc, b_enc, w_spkr, conv_w, w_proj, part);
  hipLaunchKernelGGL(ctx_prenet_kernel, dim3(64), dim3(512), 0, stream,
                     input_enc, input_dec, spkr_vec, lengths, part,
                     w_p1, b_p1, w_p2, b_p2, xbuf);
  hipLaunchKernelGGL(gemm_gates_kernel, dim3(192), dim3(512), 0, stream,
                     xbuf, 832, 832, w_ih0, b_ih0, b_hh0, gates);
  hipLaunchKernelGGL(lstm_act_kernel, dim3(256), dim3(256), 0, stream, gates, h1);
  hipLaunchKernelGGL(gemm_gates_kernel, dim3(192), dim3(512), 0, stream,
                     h1, 1024, 1024, w_ih1, b_ih1, b_hh1, gates);
  hipLaunchKernelGGL(out_kernel, dim3(64), dim3(1024), 0, stream,
                     gates, xbuf, w_out, b_out, out);
}